// Round 8
// baseline (235.743 us; speedup 1.0000x reference)
//
#include <hip/hip_runtime.h>

#define N_NODES 100000
#define N_EDGES 1600000
#define DIM 64
#define BN_EPS 1e-5f

#define BNODES 128                        // nodes per bucket (7 bits)
#define NBUCK ((N_NODES + BNODES - 1) / BNODES)  // 782
#define CAP 2560                          // entries/bucket: mean 2046, +11 sigma
#define TILE 8192                         // edges per passA block

#define GBLK 6250                         // gather blocks (4 waves x 4 nodes each)

typedef __bf16 bf16x8 __attribute__((ext_vector_type(8)));
typedef float floatx4 __attribute__((ext_vector_type(4)));

// ---- bf16 helpers (manual RNE) -------------------------------------------
static __device__ __forceinline__ unsigned short f2bf(float f) {
    unsigned u = __float_as_uint(f);
    u = (u + 0x7FFFu + ((u >> 16) & 1u)) >> 16;
    return (unsigned short)u;
}
static __device__ __forceinline__ float bf2f(unsigned short h) {
    return __uint_as_float(((unsigned)h) << 16);
}

// ---------------- passA: coarse partition into 128-node buckets -----------
__global__ void passA_kernel(const int* __restrict__ src, const int* __restrict__ dst,
                             int* __restrict__ cur, unsigned int* __restrict__ entries, int E) {
    __shared__ int hist[NBUCK];
    __shared__ int lbase[NBUCK];
    int t = threadIdx.x;
    for (int i = t; i < NBUCK; i += 256) hist[i] = 0;
    __syncthreads();

    int e0   = blockIdx.x * TILE;
    int eend = min(e0 + TILE, E);

    for (int e = e0 + t; e < eend; e += 256)
        atomicAdd(&hist[dst[e] >> 7], 1);
    __syncthreads();
    for (int i = t; i < NBUCK; i += 256) {
        int c = hist[i];
        lbase[i] = (c > 0) ? atomicAdd(&cur[i], c) : 0;
        hist[i] = 0;                      // reuse as local cursor
    }
    __syncthreads();
    for (int e = e0 + t; e < eend; e += 256) {
        int s = src[e];
        int d = dst[e];
        int b = d >> 7;
        int r = atomicAdd(&hist[b], 1);
        int pos = lbase[b] + r;
        if (pos < CAP)                    // safety valve; statistically never
            entries[(size_t)b * CAP + pos] = ((unsigned)s << 7) | (unsigned)(d & 127);
    }
}

// ---------------- passB1: in-LDS counting sort per bucket -----------------
__global__ void passB1_kernel(unsigned int* __restrict__ entries, const int* __restrict__ cur,
                              int* __restrict__ rowbeg, int* __restrict__ rowend,
                              float* __restrict__ dinv, int N) {
    __shared__ unsigned int raw[CAP];     // 10 KB
    __shared__ int hist[BNODES];
    __shared__ int sbuf[BNODES];
    __shared__ int startx[BNODES];
    __shared__ int cursor[BNODES];
    int bucket = blockIdx.x;
    int t = threadIdx.x;                  // 256 threads
    int node0 = bucket * BNODES;
    int nn = min(BNODES, N - node0);
    int cnt = min(cur[bucket], CAP);
    unsigned int* eb = entries + (size_t)bucket * CAP;

    if (t < BNODES) hist[t] = 0;
    __syncthreads();
    for (int i = t; i < cnt; i += 256) {
        unsigned int e = eb[i];
        raw[i] = e;
        atomicAdd(&hist[e & 127], 1);
    }
    __syncthreads();
    if (t < BNODES) sbuf[t] = hist[t];
    __syncthreads();
    for (int off = 1; off < BNODES; off <<= 1) {
        int add = (t < BNODES && t >= off) ? sbuf[t - off] : 0;
        __syncthreads();
        if (t < BNODES) sbuf[t] += add;
        __syncthreads();
    }
    if (t < BNODES) {
        int ex = sbuf[t] - hist[t];       // exclusive
        startx[t] = ex;
        cursor[t] = ex;
    }
    __syncthreads();
    for (int i = t; i < cnt; i += 256) {
        unsigned int e = raw[i];
        int d = e & 127;
        int p = atomicAdd(&cursor[d], 1);
        eb[p] = e >> 7;                   // store src only
    }
    if (t < nn) {
        int dg   = hist[t];               // exact degree of this node
        int base = bucket * CAP + startx[t];
        rowbeg[node0 + t] = base;
        rowend[node0 + t] = base + dg;
        dinv[node0 + t]   = rsqrtf((float)(dg + 1));  // self-loop included
    }
}

// ---------------- h' = (x @ W) * dinv[row] via bf16 MFMA ------------------
__global__ void __launch_bounds__(256)
gemm_kernel(const float* __restrict__ x, const float* __restrict__ W,
            const float* __restrict__ dinv, unsigned short* __restrict__ hb, int N) {
    int wave  = (blockIdx.x * blockDim.x + threadIdx.x) >> 6;
    int lane  = threadIdx.x & 63;
    int m     = lane & 15;
    int quad  = lane >> 4;

    bf16x8 bfrag[2][4];                   // [kchunk][ntile]
#pragma unroll
    for (int c = 0; c < 2; ++c)
#pragma unroll
        for (int nt = 0; nt < 4; ++nt) {
            bf16x8 f;
#pragma unroll
            for (int j = 0; j < 8; ++j) {
                int k = c * 32 + quad * 8 + j;
                f[j] = (__bf16)W[k * DIM + nt * 16 + m];
            }
            bfrag[c][nt] = f;
        }

    int nchunks    = N >> 4;              // 6250
    int totalwaves = (gridDim.x * blockDim.x) >> 6;
    for (int chunk = wave; chunk < nchunks; chunk += totalwaves) {
        int row0 = chunk * 16;
        const float* xr = x + (size_t)(row0 + m) * DIM;
        bf16x8 afrag[2];
#pragma unroll
        for (int c = 0; c < 2; ++c) {
            float4 lo = *(const float4*)(xr + c * 32 + quad * 8);
            float4 hi = *(const float4*)(xr + c * 32 + quad * 8 + 4);
            bf16x8 f;
            f[0] = (__bf16)lo.x; f[1] = (__bf16)lo.y; f[2] = (__bf16)lo.z; f[3] = (__bf16)lo.w;
            f[4] = (__bf16)hi.x; f[5] = (__bf16)hi.y; f[6] = (__bf16)hi.z; f[7] = (__bf16)hi.w;
            afrag[c] = f;
        }
        float dv[4];
#pragma unroll
        for (int r = 0; r < 4; ++r) dv[r] = dinv[row0 + quad * 4 + r];
#pragma unroll
        for (int nt = 0; nt < 4; ++nt) {
            floatx4 acc = {0.f, 0.f, 0.f, 0.f};
            acc = __builtin_amdgcn_mfma_f32_16x16x32_bf16(afrag[0], bfrag[0][nt], acc, 0, 0, 0);
            acc = __builtin_amdgcn_mfma_f32_16x16x32_bf16(afrag[1], bfrag[1][nt], acc, 0, 0, 0);
#pragma unroll
            for (int r = 0; r < 4; ++r) {
                int row = row0 + quad * 4 + r;
                hb[(size_t)row * DIM + nt * 16 + m] = f2bf(acc[r] * dv[r]);
            }
        }
    }
}

// ---------------- gather: 4 nodes/wave, prefix-snapshot (no routing) ------
// Merged run [rowbeg[n0], rowend[n0+3]) is contiguous; one accumulator runs
// over the whole stream and is snapshotted at the 3 wave-uniform segment
// boundaries (scalar branches, off the VALU pipe). Node sums = snapshot
// differences (error ~1 ulp of running sum). BN column partials per block
// go to a partial[] buffer (plain stores, no atomics).
__global__ void __launch_bounds__(256)
gather_kernel(const int* __restrict__ rowbeg, const int* __restrict__ rowend,
              const unsigned int* __restrict__ srt, const unsigned short* __restrict__ hb,
              const float* __restrict__ dinv, float* __restrict__ out,
              float* __restrict__ partial, int N) {
    __shared__ float red[2][4][64];
    int lane = threadIdx.x & 63;
    int wv   = threadIdx.x >> 6;
    int g    = blockIdx.x * 4 + wv;
    int n0   = g << 2;
    float s_sum = 0.f, s_sq = 0.f;

    if (n0 < N) {  // uniform per wave; N % 4 == 0
        int beg = rowbeg[n0];
        int s1  = rowbeg[n0 + 1];
        int s2  = rowbeg[n0 + 2];
        int s3  = rowbeg[n0 + 3];
        int end = rowend[n0 + 3];
        float acc = 0.f, snap1 = 0.f, snap2 = 0.f, snap3 = 0.f;

        for (int base = beg; base < end; base += 64) {
            int idx = base + lane;
            unsigned int sv = (idx < end) ? srt[idx] : 0u;  // coalesced batch
            int cn = min(64, end - base);
            int j = 0;
            while (j < cn) {
                int p0 = base + j;
                int rem = cn - j;
                bool bnd = ((unsigned)(s1 - p0) < 8u) | ((unsigned)(s2 - p0) < 8u) |
                           ((unsigned)(s3 - p0) < 8u);
                if (rem >= 8 && !bnd) {    // fast path: straight 8-wide MLP
                    float v[8];
#pragma unroll
                    for (int u = 0; u < 8; ++u) {
                        unsigned int s = __shfl(sv, j + u, 64);
                        v[u] = bf2f(hb[(size_t)s * DIM + lane]);
                    }
                    acc += ((v[0] + v[1]) + (v[2] + v[3])) + ((v[4] + v[5]) + (v[6] + v[7]));
                    j += 8;
                } else {                   // boundary/tail: per-edge + snapshots
                    int stop = min(j + 8, cn);
                    for (; j < stop; ++j) {
                        int p = base + j;
                        if (p == s1) snap1 = acc;
                        if (p == s2) snap2 = acc;
                        if (p == s3) snap3 = acc;
                        unsigned int s = __shfl(sv, j, 64);
                        acc += bf2f(hb[(size_t)s * DIM + lane]);
                    }
                }
            }
        }
        if (s1 == end) snap1 = acc;        // boundaries at stream end
        if (s2 == end) snap2 = acc;
        if (s3 == end) snap3 = acc;

        float g0 = snap1;
        float g1 = snap2 - snap1;
        float g2 = snap3 - snap2;
        float g3 = acc - snap3;
        float v0 = (g0 + bf2f(hb[(size_t)(n0 + 0) * DIM + lane])) * dinv[n0 + 0];
        float v1 = (g1 + bf2f(hb[(size_t)(n0 + 1) * DIM + lane])) * dinv[n0 + 1];
        float v2 = (g2 + bf2f(hb[(size_t)(n0 + 2) * DIM + lane])) * dinv[n0 + 2];
        float v3 = (g3 + bf2f(hb[(size_t)(n0 + 3) * DIM + lane])) * dinv[n0 + 3];
        out[(size_t)(n0 + 0) * DIM + lane] = v0;
        out[(size_t)(n0 + 1) * DIM + lane] = v1;
        out[(size_t)(n0 + 2) * DIM + lane] = v2;
        out[(size_t)(n0 + 3) * DIM + lane] = v3;
        s_sum = ((v0 + v1) + (v2 + v3));
        s_sq  = ((v0 * v0 + v1 * v1) + (v2 * v2 + v3 * v3));
    }

    red[0][wv][lane] = s_sum;
    red[1][wv][lane] = s_sq;
    __syncthreads();
    if (threadIdx.x < 64) {
        int c = threadIdx.x;
        partial[(size_t)blockIdx.x * 128 + c] =
            red[0][0][c] + red[0][1][c] + red[0][2][c] + red[0][3][c];
        partial[(size_t)blockIdx.x * 128 + 64 + c] =
            red[1][0][c] + red[1][1][c] + red[1][2][c] + red[1][3][c];
    }
}

// ---------------- reduce2: fold per-block BN partials ---------------------
__global__ void reduce2_kernel(const float* __restrict__ partial, float* __restrict__ gstat) {
    __shared__ float buf[256];
    int t = threadIdx.x;
    int col = t & 127;
    int half = t >> 7;                    // 0 or 1
    int r0 = blockIdx.x * 125;            // 50 blocks x 125 rows = 6250
    float acc = 0.f;
    for (int r = r0 + half; r < r0 + 125; r += 2)
        acc += partial[(size_t)r * 128 + col];
    buf[t] = acc;
    __syncthreads();
    if (t < 128) atomicAdd(&gstat[t], buf[t] + buf[t + 128]);  // gsum[64]|gsumsq[64]
}

// ---------------- BN finalize: scale/shift per column ---------------------
// bias b cancels in BN (uniform per-column shift), so it's omitted entirely.
__global__ void bn_finalize_kernel(const float* __restrict__ gsum, const float* __restrict__ gsumsq,
                                   const float* __restrict__ gamma, const float* __restrict__ beta,
                                   float* __restrict__ scale, float* __restrict__ shift, int N) {
    int c = threadIdx.x;  // 64 threads
    float invN = 1.0f / (float)N;
    float mean = gsum[c] * invN;
    float var  = gsumsq[c] * invN - mean * mean;
    float sc   = gamma[c] * rsqrtf(var + BN_EPS);
    scale[c] = sc;
    shift[c] = beta[c] - mean * sc;
}

// ---------------- BN apply + ReLU, in place, float4 -----------------------
__global__ void bn_apply_kernel(float4* __restrict__ out, const float* __restrict__ scale,
                                const float* __restrict__ shift, int total4) {
    int i = blockIdx.x * blockDim.x + threadIdx.x;
    if (i >= total4) return;
    int c = (i * 4) & 63;
    float4 v = out[i];
    float a0 = fmaf(v.x, scale[c],     shift[c]);
    float a1 = fmaf(v.y, scale[c + 1], shift[c + 1]);
    float a2 = fmaf(v.z, scale[c + 2], shift[c + 2]);
    float a3 = fmaf(v.w, scale[c + 3], shift[c + 3]);
    v.x = a0 > 0.f ? a0 : 0.f;
    v.y = a1 > 0.f ? a1 : 0.f;
    v.z = a2 > 0.f ? a2 : 0.f;
    v.w = a3 > 0.f ? a3 : 0.f;
    out[i] = v;
}

extern "C" void kernel_launch(void* const* d_in, const int* in_sizes, int n_in,
                              void* d_out, int out_size, void* d_ws, size_t ws_size,
                              hipStream_t stream) {
    const float* x     = (const float*)d_in[0];          // [N, 64]
    const int*   eidx  = (const int*)d_in[1];            // [2, E]
    const float* W     = (const float*)d_in[2];          // [64, 64]
    // d_in[3] = b : cancels in BatchNorm (uniform per-column shift)
    const float* gamma = (const float*)d_in[4];          // [64]
    const float* beta  = (const float*)d_in[5];          // [64]
    float* out = (float*)d_out;                          // [N, 64]

    const int N = N_NODES;
    const int E = N_EDGES;
    const int total = N * DIM;

    const int* src = eidx;
    const int* dst = eidx + E;

    // workspace layout (~25.6 MB)
    unsigned short* hb = (unsigned short*)d_ws;            // N*DIM bf16 (12.8 MB)
    float* dinv      = (float*)(hb + (size_t)N * DIM);     // N
    int*   rowbeg    = (int*)(dinv + N);                   // N
    int*   rowend    = rowbeg + N;                         // N
    int*   cur       = rowend + N;                         // NBUCK } one
    float* gsum      = (float*)(cur + NBUCK);              // 64    } memset
    float* gsumsq    = gsum + 64;                          // 64    } region
    float* scale     = gsumsq + 64;                        // 64
    float* shift     = scale + 64;                         // 64
    unsigned int* entries = (unsigned int*)(shift + 64);   // NBUCK*CAP (8.0 MB)
    float* partial   = (float*)(entries + (size_t)NBUCK * CAP);  // GBLK*128 (3.2 MB)

    // zero cur + gsum + gsumsq in one memset
    hipMemsetAsync(cur, 0, (size_t)(NBUCK + 128) * sizeof(int), stream);

    int nblkA = (E + TILE - 1) / TILE;  // 196
    passA_kernel<<<nblkA, 256, 0, stream>>>(src, dst, cur, entries, E);

    passB1_kernel<<<NBUCK, 256, 0, stream>>>(entries, cur, rowbeg, rowend, dinv, N);

    gemm_kernel<<<512, 256, 0, stream>>>(x, W, dinv, hb, N);

    gather_kernel<<<GBLK, 256, 0, stream>>>(rowbeg, rowend, entries, hb, dinv, out, partial, N);

    reduce2_kernel<<<50, 256, 0, stream>>>(partial, gsum);

    bn_finalize_kernel<<<1, 64, 0, stream>>>(gsum, gsumsq, gamma, beta, scale, shift, N);
    bn_apply_kernel<<<(total / 4 + 255) / 256, 256, 0, stream>>>((float4*)out, scale, shift, total / 4);
}

// Round 9
// 210.795 us; speedup vs baseline: 1.1184x; 1.1184x over previous
//
#include <hip/hip_runtime.h>

#define N_NODES 100000
#define N_EDGES 1600000
#define DIM 64
#define BN_EPS 1e-5f

#define BNODES 128                        // nodes per bucket (7 bits)
#define NBUCK ((N_NODES + BNODES - 1) / BNODES)  // 782
#define CAP_RAW 2560                      // raw entries/bucket: mean 2046, +11 sigma
#define CAP_OUT 3584                      // sorted+padded: CAP_RAW + 128*7 = 3456, rounded up
#define TILE 8192                         // edges per passA block
#define DUMMY N_NODES                     // pad index -> zeroed hb row N

#define GBLK 6250                         // gather blocks (4 waves x 4 nodes each)

typedef __bf16 bf16x8 __attribute__((ext_vector_type(8)));
typedef float floatx4 __attribute__((ext_vector_type(4)));

// ---- bf16 helpers (manual RNE) -------------------------------------------
static __device__ __forceinline__ unsigned short f2bf(float f) {
    unsigned u = __float_as_uint(f);
    u = (u + 0x7FFFu + ((u >> 16) & 1u)) >> 16;
    return (unsigned short)u;
}
static __device__ __forceinline__ float bf2f(unsigned short h) {
    return __uint_as_float(((unsigned)h) << 16);
}

// ---------------- passA: coarse partition into 128-node buckets -----------
__global__ void passA_kernel(const int* __restrict__ src, const int* __restrict__ dst,
                             int* __restrict__ cur, unsigned int* __restrict__ entries, int E) {
    __shared__ int hist[NBUCK];
    __shared__ int lbase[NBUCK];
    int t = threadIdx.x;
    for (int i = t; i < NBUCK; i += 256) hist[i] = 0;
    __syncthreads();

    int e0   = blockIdx.x * TILE;
    int eend = min(e0 + TILE, E);

    for (int e = e0 + t; e < eend; e += 256)
        atomicAdd(&hist[dst[e] >> 7], 1);
    __syncthreads();
    for (int i = t; i < NBUCK; i += 256) {
        int c = hist[i];
        lbase[i] = (c > 0) ? atomicAdd(&cur[i], c) : 0;
        hist[i] = 0;                      // reuse as local cursor
    }
    __syncthreads();
    for (int e = e0 + t; e < eend; e += 256) {
        int s = src[e];
        int d = dst[e];
        int b = d >> 7;
        int r = atomicAdd(&hist[b], 1);
        int pos = lbase[b] + r;
        if (pos < CAP_RAW)                // safety valve; statistically never
            entries[(size_t)b * CAP_OUT + pos] = ((unsigned)s << 7) | (unsigned)(d & 127);
    }
}

// ---------------- passB1: in-LDS counting sort, 8-padded segments ---------
// Each node's segment is padded to a multiple of 8 with DUMMY entries
// (hb row N = zeros), so gather chunks never straddle a segment boundary.
__global__ void passB1_kernel(unsigned int* __restrict__ entries, const int* __restrict__ cur,
                              int* __restrict__ rowbeg, int* __restrict__ rowend,
                              float* __restrict__ dinv, int N) {
    __shared__ unsigned int raw[CAP_RAW]; // 10 KB
    __shared__ int hist[BNODES];
    __shared__ int sbuf[BNODES];
    __shared__ int startx[BNODES];
    __shared__ int cursor[BNODES];
    int bucket = blockIdx.x;
    int t = threadIdx.x;                  // 256 threads
    int node0 = bucket * BNODES;
    int nn = min(BNODES, N - node0);
    int cnt = min(cur[bucket], CAP_RAW);
    unsigned int* eb = entries + (size_t)bucket * CAP_OUT;

    if (t < BNODES) hist[t] = 0;
    __syncthreads();
    for (int i = t; i < cnt; i += 256) {
        unsigned int e = eb[i];
        raw[i] = e;
        atomicAdd(&hist[e & 127], 1);
    }
    __syncthreads();
    int pdeg_t = 0;
    if (t < BNODES) { pdeg_t = (hist[t] + 7) & ~7; sbuf[t] = pdeg_t; }
    __syncthreads();
    for (int off = 1; off < BNODES; off <<= 1) {
        int add = (t < BNODES && t >= off) ? sbuf[t - off] : 0;
        __syncthreads();
        if (t < BNODES) sbuf[t] += add;
        __syncthreads();
    }
    if (t < BNODES) {
        int ex = sbuf[t] - pdeg_t;        // exclusive padded scan
        startx[t] = ex;
        cursor[t] = ex;
    }
    __syncthreads();
    for (int i = t; i < cnt; i += 256) {
        unsigned int e = raw[i];
        int d = e & 127;
        int p = atomicAdd(&cursor[d], 1);
        eb[p] = e >> 7;                   // store src only
    }
    if (t < nn) {
        int dg  = hist[t];                // exact degree of this node
        int pdg = (dg + 7) & ~7;
        int base = startx[t];
        for (int k = dg; k < pdg; ++k) eb[base + k] = DUMMY;  // disjoint from scatter
        int gbase = bucket * CAP_OUT + base;
        rowbeg[node0 + t] = gbase;
        rowend[node0 + t] = gbase + pdg;
        dinv[node0 + t]   = rsqrtf((float)(dg + 1));  // self-loop included
    }
}

// ---------------- h' = (x @ W) * dinv[row] via bf16 MFMA ------------------
__global__ void __launch_bounds__(256)
gemm_kernel(const float* __restrict__ x, const float* __restrict__ W,
            const float* __restrict__ dinv, unsigned short* __restrict__ hb, int N) {
    int wave  = (blockIdx.x * blockDim.x + threadIdx.x) >> 6;
    int lane  = threadIdx.x & 63;
    int m     = lane & 15;
    int quad  = lane >> 4;

    bf16x8 bfrag[2][4];                   // [kchunk][ntile]
#pragma unroll
    for (int c = 0; c < 2; ++c)
#pragma unroll
        for (int nt = 0; nt < 4; ++nt) {
            bf16x8 f;
#pragma unroll
            for (int j = 0; j < 8; ++j) {
                int k = c * 32 + quad * 8 + j;
                f[j] = (__bf16)W[k * DIM + nt * 16 + m];
            }
            bfrag[c][nt] = f;
        }

    int nchunks    = N >> 4;              // 6250
    int totalwaves = (gridDim.x * blockDim.x) >> 6;
    for (int chunk = wave; chunk < nchunks; chunk += totalwaves) {
        int row0 = chunk * 16;
        const float* xr = x + (size_t)(row0 + m) * DIM;
        bf16x8 afrag[2];
#pragma unroll
        for (int c = 0; c < 2; ++c) {
            float4 lo = *(const float4*)(xr + c * 32 + quad * 8);
            float4 hi = *(const float4*)(xr + c * 32 + quad * 8 + 4);
            bf16x8 f;
            f[0] = (__bf16)lo.x; f[1] = (__bf16)lo.y; f[2] = (__bf16)lo.z; f[3] = (__bf16)lo.w;
            f[4] = (__bf16)hi.x; f[5] = (__bf16)hi.y; f[6] = (__bf16)hi.z; f[7] = (__bf16)hi.w;
            afrag[c] = f;
        }
        float dv[4];
#pragma unroll
        for (int r = 0; r < 4; ++r) dv[r] = dinv[row0 + quad * 4 + r];
#pragma unroll
        for (int nt = 0; nt < 4; ++nt) {
            floatx4 acc = {0.f, 0.f, 0.f, 0.f};
            acc = __builtin_amdgcn_mfma_f32_16x16x32_bf16(afrag[0], bfrag[0][nt], acc, 0, 0, 0);
            acc = __builtin_amdgcn_mfma_f32_16x16x32_bf16(afrag[1], bfrag[1][nt], acc, 0, 0, 0);
#pragma unroll
            for (int r = 0; r < 4; ++r) {
                int row = row0 + quad * 4 + r;
                hb[(size_t)row * DIM + nt * 16 + m] = f2bf(acc[r] * dv[r]);
            }
        }
    }
}

// ---------------- gather: 4 nodes/wave, chunk-aligned routing -------------
// Segments are 8-padded, so each 8-edge chunk belongs to exactly one node:
// segment id = 3 scalar compares per chunk; routing = 4 cndmask adds per
// chunk (1/edge vs 8/edge in r7). Inner loop is branch-free: 8 loads batch.
__global__ void __launch_bounds__(256)
gather_kernel(const int* __restrict__ rowbeg, const int* __restrict__ rowend,
              const unsigned int* __restrict__ srt, const unsigned short* __restrict__ hb,
              const float* __restrict__ dinv, float* __restrict__ out,
              float* __restrict__ partial, int N) {
    __shared__ float red[2][4][64];
    int lane = threadIdx.x & 63;
    int wv   = threadIdx.x >> 6;
    int g    = blockIdx.x * 4 + wv;
    int n0   = g << 2;
    float s_sum = 0.f, s_sq = 0.f;

    if (n0 < N) {  // uniform per wave; N % 4 == 0; groups never straddle buckets
        int beg = __builtin_amdgcn_readfirstlane(rowbeg[n0]);
        int s1  = __builtin_amdgcn_readfirstlane(rowbeg[n0 + 1]);
        int s2  = __builtin_amdgcn_readfirstlane(rowbeg[n0 + 2]);
        int s3  = __builtin_amdgcn_readfirstlane(rowbeg[n0 + 3]);
        int end = __builtin_amdgcn_readfirstlane(rowend[n0 + 3]);
        float acc0 = 0.f, acc1 = 0.f, acc2 = 0.f, acc3 = 0.f;

        for (int base = beg; base < end; base += 64) {
            int idx = base + lane;
            unsigned int sv = (idx < end) ? srt[idx] : 0u;  // coalesced batch
            int cn = min(64, end - base);                   // multiple of 8
            for (int j = 0; j < cn; j += 8) {
                int p0 = base + j;                          // uniform (SALU)
                int k = (p0 >= s1) + (p0 >= s2) + (p0 >= s3);
                float v[8];
#pragma unroll
                for (int u = 0; u < 8; ++u) {
                    unsigned int s = (unsigned)__shfl((int)sv, j + u, 64);
                    v[u] = bf2f(hb[(size_t)s * DIM + lane]);
                }
                float csum = ((v[0] + v[1]) + (v[2] + v[3])) +
                             ((v[4] + v[5]) + (v[6] + v[7]));
                acc0 += (k == 0) ? csum : 0.f;
                acc1 += (k == 1) ? csum : 0.f;
                acc2 += (k == 2) ? csum : 0.f;
                acc3 += (k == 3) ? csum : 0.f;
            }
        }

        float v0 = (acc0 + bf2f(hb[(size_t)(n0 + 0) * DIM + lane])) * dinv[n0 + 0];
        float v1 = (acc1 + bf2f(hb[(size_t)(n0 + 1) * DIM + lane])) * dinv[n0 + 1];
        float v2 = (acc2 + bf2f(hb[(size_t)(n0 + 2) * DIM + lane])) * dinv[n0 + 2];
        float v3 = (acc3 + bf2f(hb[(size_t)(n0 + 3) * DIM + lane])) * dinv[n0 + 3];
        out[(size_t)(n0 + 0) * DIM + lane] = v0;
        out[(size_t)(n0 + 1) * DIM + lane] = v1;
        out[(size_t)(n0 + 2) * DIM + lane] = v2;
        out[(size_t)(n0 + 3) * DIM + lane] = v3;
        s_sum = ((v0 + v1) + (v2 + v3));
        s_sq  = ((v0 * v0 + v1 * v1) + (v2 * v2 + v3 * v3));
    }

    red[0][wv][lane] = s_sum;
    red[1][wv][lane] = s_sq;
    __syncthreads();
    if (threadIdx.x < 64) {
        int c = threadIdx.x;
        partial[(size_t)blockIdx.x * 128 + c] =
            red[0][0][c] + red[0][1][c] + red[0][2][c] + red[0][3][c];
        partial[(size_t)blockIdx.x * 128 + 64 + c] =
            red[1][0][c] + red[1][1][c] + red[1][2][c] + red[1][3][c];
    }
}

// ---------------- reduce2: fold per-block BN partials ---------------------
__global__ void reduce2_kernel(const float* __restrict__ partial, float* __restrict__ gstat) {
    __shared__ float buf[256];
    int t = threadIdx.x;
    int col = t & 127;
    int half = t >> 7;                    // 0 or 1
    int r0 = blockIdx.x * 125;            // 50 blocks x 125 rows = 6250
    float acc = 0.f;
    for (int r = r0 + half; r < r0 + 125; r += 2)
        acc += partial[(size_t)r * 128 + col];
    buf[t] = acc;
    __syncthreads();
    if (t < 128) atomicAdd(&gstat[t], buf[t] + buf[t + 128]);  // gsum[64]|gsumsq[64]
}

// ---------------- BN finalize: scale/shift per column ---------------------
// bias b cancels in BN (uniform per-column shift), so it's omitted entirely.
__global__ void bn_finalize_kernel(const float* __restrict__ gsum, const float* __restrict__ gsumsq,
                                   const float* __restrict__ gamma, const float* __restrict__ beta,
                                   float* __restrict__ scale, float* __restrict__ shift, int N) {
    int c = threadIdx.x;  // 64 threads
    float invN = 1.0f / (float)N;
    float mean = gsum[c] * invN;
    float var  = gsumsq[c] * invN - mean * mean;
    float sc   = gamma[c] * rsqrtf(var + BN_EPS);
    scale[c] = sc;
    shift[c] = beta[c] - mean * sc;
}

// ---------------- BN apply + ReLU, in place, float4 -----------------------
__global__ void bn_apply_kernel(float4* __restrict__ out, const float* __restrict__ scale,
                                const float* __restrict__ shift, int total4) {
    int i = blockIdx.x * blockDim.x + threadIdx.x;
    if (i >= total4) return;
    int c = (i * 4) & 63;
    float4 v = out[i];
    float a0 = fmaf(v.x, scale[c],     shift[c]);
    float a1 = fmaf(v.y, scale[c + 1], shift[c + 1]);
    float a2 = fmaf(v.z, scale[c + 2], shift[c + 2]);
    float a3 = fmaf(v.w, scale[c + 3], shift[c + 3]);
    v.x = a0 > 0.f ? a0 : 0.f;
    v.y = a1 > 0.f ? a1 : 0.f;
    v.z = a2 > 0.f ? a2 : 0.f;
    v.w = a3 > 0.f ? a3 : 0.f;
    out[i] = v;
}

extern "C" void kernel_launch(void* const* d_in, const int* in_sizes, int n_in,
                              void* d_out, int out_size, void* d_ws, size_t ws_size,
                              hipStream_t stream) {
    const float* x     = (const float*)d_in[0];          // [N, 64]
    const int*   eidx  = (const int*)d_in[1];            // [2, E]
    const float* W     = (const float*)d_in[2];          // [64, 64]
    // d_in[3] = b : cancels in BatchNorm (uniform per-column shift)
    const float* gamma = (const float*)d_in[4];          // [64]
    const float* beta  = (const float*)d_in[5];          // [64]
    float* out = (float*)d_out;                          // [N, 64]

    const int N = N_NODES;
    const int E = N_EDGES;
    const int total = N * DIM;

    const int* src = eidx;
    const int* dst = eidx + E;

    // workspace layout (~28.5 MB)
    unsigned short* hb = (unsigned short*)d_ws;            // (N+1)*DIM bf16; row N = zeros
    float* dinv      = (float*)(hb + (size_t)(N + 1) * DIM); // N
    int*   rowbeg    = (int*)(dinv + N);                   // N
    int*   rowend    = rowbeg + N;                         // N
    int*   cur       = rowend + N;                         // NBUCK } one
    float* gsum      = (float*)(cur + NBUCK);              // 64    } memset
    float* gsumsq    = gsum + 64;                          // 64    } region
    float* scale     = gsumsq + 64;                        // 64
    float* shift     = scale + 64;                         // 64
    unsigned int* entries = (unsigned int*)(shift + 64);   // NBUCK*CAP_OUT (11.2 MB)
    float* partial   = (float*)(entries + (size_t)NBUCK * CAP_OUT);  // GBLK*128 (3.2 MB)

    // zero cur + gsum + gsumsq, and the dummy hb row N
    hipMemsetAsync(cur, 0, (size_t)(NBUCK + 128) * sizeof(int), stream);
    hipMemsetAsync(hb + (size_t)N * DIM, 0, DIM * sizeof(unsigned short), stream);

    int nblkA = (E + TILE - 1) / TILE;  // 196
    passA_kernel<<<nblkA, 256, 0, stream>>>(src, dst, cur, entries, E);

    passB1_kernel<<<NBUCK, 256, 0, stream>>>(entries, cur, rowbeg, rowend, dinv, N);

    gemm_kernel<<<512, 256, 0, stream>>>(x, W, dinv, hb, N);

    gather_kernel<<<GBLK, 256, 0, stream>>>(rowbeg, rowend, entries, hb, dinv, out, partial, N);

    reduce2_kernel<<<50, 256, 0, stream>>>(partial, gsum);

    bn_finalize_kernel<<<1, 64, 0, stream>>>(gsum, gsumsq, gamma, beta, scale, shift, N);
    bn_apply_kernel<<<(total / 4 + 255) / 256, 256, 0, stream>>>((float4*)out, scale, shift, total / 4);
}

// Round 10
// 197.386 us; speedup vs baseline: 1.1943x; 1.0679x over previous
//
#include <hip/hip_runtime.h>

#define N_NODES 100000
#define N_EDGES 1600000
#define DIM 64
#define BN_EPS 1e-5f

#define BNODES 128                        // nodes per bucket (7 bits)
#define NBUCK ((N_NODES + BNODES - 1) / BNODES)  // 782
#define CAP_RAW 2560                      // raw entries/bucket: mean 2046, +11 sigma
#define CAP_OUT 3584                      // sorted+padded: CAP_RAW + 128*7 = 3456, rounded up
#define TILE 4096                         // edges per passA block
#define ABLK ((N_EDGES + TILE - 1) / TILE)  // 391
#define DUMMY N_NODES                     // pad index -> zeroed hb row N

#define GBLK 6250                         // gather blocks (4 waves x 4 nodes each)

typedef __bf16 bf16x8 __attribute__((ext_vector_type(8)));
typedef float floatx4 __attribute__((ext_vector_type(4)));

// ---- bf16 helpers (manual RNE) -------------------------------------------
static __device__ __forceinline__ unsigned short f2bf(float f) {
    unsigned u = __float_as_uint(f);
    u = (u + 0x7FFFu + ((u >> 16) & 1u)) >> 16;
    return (unsigned short)u;
}
static __device__ __forceinline__ float bf2f(unsigned short h) {
    return __uint_as_float(((unsigned)h) << 16);
}

// ---------------- passA: coarse partition into 128-node buckets -----------
// r9 ran this at 196 blocks x 4 waves = 6% occupancy -> latency-bound.
// Now 391 blocks x 16 waves (~24 waves/CU); 4 edges/thread held in
// registers across both phases; bucket reservation loop staggered per
// block to de-burst same-line global-atomic contention.
__global__ void __launch_bounds__(1024)
passA_kernel(const int* __restrict__ src, const int* __restrict__ dst,
             int* __restrict__ cur, unsigned int* __restrict__ entries, int E) {
    __shared__ int hist[NBUCK];
    __shared__ int lbase[NBUCK];
    int t = threadIdx.x;
    if (t < NBUCK) hist[t] = 0;
    __syncthreads();

    int e0   = blockIdx.x * TILE;
    int eend = min(e0 + TILE, E);

    int dreg[4], sreg[4], ne = 0;
    for (int e = e0 + t; e < eend; e += 1024) {
        dreg[ne] = dst[e];
        sreg[ne] = src[e];
        atomicAdd(&hist[dreg[ne] >> 7], 1);
        ++ne;
    }
    __syncthreads();
    if (t < NBUCK) {
        int ii = t + (blockIdx.x * 331) % NBUCK;   // staggered start
        if (ii >= NBUCK) ii -= NBUCK;
        int c = hist[ii];
        lbase[ii] = (c > 0) ? atomicAdd(&cur[ii], c) : 0;
        hist[ii] = 0;                      // reuse as local cursor
    }
    __syncthreads();
    for (int k = 0; k < ne; ++k) {
        int s = sreg[k];
        int d = dreg[k];
        int b = d >> 7;
        int r = atomicAdd(&hist[b], 1);
        int pos = lbase[b] + r;
        if (pos < CAP_RAW)                // safety valve; statistically never
            entries[(size_t)b * CAP_OUT + pos] = ((unsigned)s << 7) | (unsigned)(d & 127);
    }
}

// ---------------- passB1: in-LDS counting sort, 8-padded segments ---------
// Each node's segment is padded to a multiple of 8 with DUMMY entries
// (hb row N = zeros), so gather chunks never straddle a segment boundary.
__global__ void passB1_kernel(unsigned int* __restrict__ entries, const int* __restrict__ cur,
                              int* __restrict__ rowbeg, int* __restrict__ rowend,
                              float* __restrict__ dinv, int N) {
    __shared__ unsigned int raw[CAP_RAW]; // 10 KB
    __shared__ int hist[BNODES];
    __shared__ int sbuf[BNODES];
    __shared__ int startx[BNODES];
    __shared__ int cursor[BNODES];
    int bucket = blockIdx.x;
    int t = threadIdx.x;                  // 256 threads
    int node0 = bucket * BNODES;
    int nn = min(BNODES, N - node0);
    int cnt = min(cur[bucket], CAP_RAW);
    unsigned int* eb = entries + (size_t)bucket * CAP_OUT;

    if (t < BNODES) hist[t] = 0;
    __syncthreads();
    for (int i = t; i < cnt; i += 256) {
        unsigned int e = eb[i];
        raw[i] = e;
        atomicAdd(&hist[e & 127], 1);
    }
    __syncthreads();
    int pdeg_t = 0;
    if (t < BNODES) { pdeg_t = (hist[t] + 7) & ~7; sbuf[t] = pdeg_t; }
    __syncthreads();
    for (int off = 1; off < BNODES; off <<= 1) {
        int add = (t < BNODES && t >= off) ? sbuf[t - off] : 0;
        __syncthreads();
        if (t < BNODES) sbuf[t] += add;
        __syncthreads();
    }
    if (t < BNODES) {
        int ex = sbuf[t] - pdeg_t;        // exclusive padded scan
        startx[t] = ex;
        cursor[t] = ex;
    }
    __syncthreads();
    for (int i = t; i < cnt; i += 256) {
        unsigned int e = raw[i];
        int d = e & 127;
        int p = atomicAdd(&cursor[d], 1);
        eb[p] = e >> 7;                   // store src only
    }
    if (t < nn) {
        int dg  = hist[t];                // exact degree of this node
        int pdg = (dg + 7) & ~7;
        int base = startx[t];
        for (int k = dg; k < pdg; ++k) eb[base + k] = DUMMY;  // disjoint from scatter
        int gbase = bucket * CAP_OUT + base;
        rowbeg[node0 + t] = gbase;
        rowend[node0 + t] = gbase + pdg;
        dinv[node0 + t]   = rsqrtf((float)(dg + 1));  // self-loop included
    }
}

// ---------------- h' = (x @ W) * dinv[row] via bf16 MFMA ------------------
__global__ void __launch_bounds__(256)
gemm_kernel(const float* __restrict__ x, const float* __restrict__ W,
            const float* __restrict__ dinv, unsigned short* __restrict__ hb, int N) {
    int wave  = (blockIdx.x * blockDim.x + threadIdx.x) >> 6;
    int lane  = threadIdx.x & 63;
    int m     = lane & 15;
    int quad  = lane >> 4;

    bf16x8 bfrag[2][4];                   // [kchunk][ntile]
#pragma unroll
    for (int c = 0; c < 2; ++c)
#pragma unroll
        for (int nt = 0; nt < 4; ++nt) {
            bf16x8 f;
#pragma unroll
            for (int j = 0; j < 8; ++j) {
                int k = c * 32 + quad * 8 + j;
                f[j] = (__bf16)W[k * DIM + nt * 16 + m];
            }
            bfrag[c][nt] = f;
        }

    int nchunks    = N >> 4;              // 6250
    int totalwaves = (gridDim.x * blockDim.x) >> 6;
    for (int chunk = wave; chunk < nchunks; chunk += totalwaves) {
        int row0 = chunk * 16;
        const float* xr = x + (size_t)(row0 + m) * DIM;
        bf16x8 afrag[2];
#pragma unroll
        for (int c = 0; c < 2; ++c) {
            float4 lo = *(const float4*)(xr + c * 32 + quad * 8);
            float4 hi = *(const float4*)(xr + c * 32 + quad * 8 + 4);
            bf16x8 f;
            f[0] = (__bf16)lo.x; f[1] = (__bf16)lo.y; f[2] = (__bf16)lo.z; f[3] = (__bf16)lo.w;
            f[4] = (__bf16)hi.x; f[5] = (__bf16)hi.y; f[6] = (__bf16)hi.z; f[7] = (__bf16)hi.w;
            afrag[c] = f;
        }
        float dv[4];
#pragma unroll
        for (int r = 0; r < 4; ++r) dv[r] = dinv[row0 + quad * 4 + r];
#pragma unroll
        for (int nt = 0; nt < 4; ++nt) {
            floatx4 acc = {0.f, 0.f, 0.f, 0.f};
            acc = __builtin_amdgcn_mfma_f32_16x16x32_bf16(afrag[0], bfrag[0][nt], acc, 0, 0, 0);
            acc = __builtin_amdgcn_mfma_f32_16x16x32_bf16(afrag[1], bfrag[1][nt], acc, 0, 0, 0);
#pragma unroll
            for (int r = 0; r < 4; ++r) {
                int row = row0 + quad * 4 + r;
                hb[(size_t)row * DIM + nt * 16 + m] = f2bf(acc[r] * dv[r]);
            }
        }
    }
}

// ---------------- gather: 4 nodes/wave, chunk-aligned routing -------------
__global__ void __launch_bounds__(256)
gather_kernel(const int* __restrict__ rowbeg, const int* __restrict__ rowend,
              const unsigned int* __restrict__ srt, const unsigned short* __restrict__ hb,
              const float* __restrict__ dinv, float* __restrict__ out,
              float* __restrict__ partial, int N) {
    __shared__ float red[2][4][64];
    int lane = threadIdx.x & 63;
    int wv   = threadIdx.x >> 6;
    int g    = blockIdx.x * 4 + wv;
    int n0   = g << 2;
    float s_sum = 0.f, s_sq = 0.f;

    if (n0 < N) {  // uniform per wave; N % 4 == 0; groups never straddle buckets
        int beg = __builtin_amdgcn_readfirstlane(rowbeg[n0]);
        int s1  = __builtin_amdgcn_readfirstlane(rowbeg[n0 + 1]);
        int s2  = __builtin_amdgcn_readfirstlane(rowbeg[n0 + 2]);
        int s3  = __builtin_amdgcn_readfirstlane(rowbeg[n0 + 3]);
        int end = __builtin_amdgcn_readfirstlane(rowend[n0 + 3]);
        float acc0 = 0.f, acc1 = 0.f, acc2 = 0.f, acc3 = 0.f;

        for (int base = beg; base < end; base += 64) {
            int idx = base + lane;
            unsigned int sv = (idx < end) ? srt[idx] : 0u;  // coalesced batch
            int cn = min(64, end - base);                   // multiple of 8
            for (int j = 0; j < cn; j += 8) {
                int p0 = base + j;                          // uniform (SALU)
                int k = (p0 >= s1) + (p0 >= s2) + (p0 >= s3);
                float v[8];
#pragma unroll
                for (int u = 0; u < 8; ++u) {
                    unsigned int s = (unsigned)__shfl((int)sv, j + u, 64);
                    v[u] = bf2f(hb[(size_t)s * DIM + lane]);
                }
                float csum = ((v[0] + v[1]) + (v[2] + v[3])) +
                             ((v[4] + v[5]) + (v[6] + v[7]));
                acc0 += (k == 0) ? csum : 0.f;
                acc1 += (k == 1) ? csum : 0.f;
                acc2 += (k == 2) ? csum : 0.f;
                acc3 += (k == 3) ? csum : 0.f;
            }
        }

        float v0 = (acc0 + bf2f(hb[(size_t)(n0 + 0) * DIM + lane])) * dinv[n0 + 0];
        float v1 = (acc1 + bf2f(hb[(size_t)(n0 + 1) * DIM + lane])) * dinv[n0 + 1];
        float v2 = (acc2 + bf2f(hb[(size_t)(n0 + 2) * DIM + lane])) * dinv[n0 + 2];
        float v3 = (acc3 + bf2f(hb[(size_t)(n0 + 3) * DIM + lane])) * dinv[n0 + 3];
        out[(size_t)(n0 + 0) * DIM + lane] = v0;
        out[(size_t)(n0 + 1) * DIM + lane] = v1;
        out[(size_t)(n0 + 2) * DIM + lane] = v2;
        out[(size_t)(n0 + 3) * DIM + lane] = v3;
        s_sum = ((v0 + v1) + (v2 + v3));
        s_sq  = ((v0 * v0 + v1 * v1) + (v2 * v2 + v3 * v3));
    }

    red[0][wv][lane] = s_sum;
    red[1][wv][lane] = s_sq;
    __syncthreads();
    if (threadIdx.x < 64) {
        int c = threadIdx.x;
        partial[(size_t)blockIdx.x * 128 + c] =
            red[0][0][c] + red[0][1][c] + red[0][2][c] + red[0][3][c];
        partial[(size_t)blockIdx.x * 128 + 64 + c] =
            red[1][0][c] + red[1][1][c] + red[1][2][c] + red[1][3][c];
    }
}

// ---------------- reduce2: fold per-block BN partials ---------------------
__global__ void reduce2_kernel(const float* __restrict__ partial, float* __restrict__ gstat) {
    __shared__ float buf[256];
    int t = threadIdx.x;
    int col = t & 127;
    int half = t >> 7;                    // 0 or 1
    int r0 = blockIdx.x * 125;            // 50 blocks x 125 rows = 6250
    float acc = 0.f;
    for (int r = r0 + half; r < r0 + 125; r += 2)
        acc += partial[(size_t)r * 128 + col];
    buf[t] = acc;
    __syncthreads();
    if (t < 128) atomicAdd(&gstat[t], buf[t] + buf[t + 128]);  // gsum[64]|gsumsq[64]
}

// ---------------- BN finalize: scale/shift per column ---------------------
// bias b cancels in BN (uniform per-column shift), so it's omitted entirely.
__global__ void bn_finalize_kernel(const float* __restrict__ gsum, const float* __restrict__ gsumsq,
                                   const float* __restrict__ gamma, const float* __restrict__ beta,
                                   float* __restrict__ scale, float* __restrict__ shift, int N) {
    int c = threadIdx.x;  // 64 threads
    float invN = 1.0f / (float)N;
    float mean = gsum[c] * invN;
    float var  = gsumsq[c] * invN - mean * mean;
    float sc   = gamma[c] * rsqrtf(var + BN_EPS);
    scale[c] = sc;
    shift[c] = beta[c] - mean * sc;
}

// ---------------- BN apply + ReLU, in place, float4 -----------------------
__global__ void bn_apply_kernel(float4* __restrict__ out, const float* __restrict__ scale,
                                const float* __restrict__ shift, int total4) {
    int i = blockIdx.x * blockDim.x + threadIdx.x;
    if (i >= total4) return;
    int c = (i * 4) & 63;
    float4 v = out[i];
    float a0 = fmaf(v.x, scale[c],     shift[c]);
    float a1 = fmaf(v.y, scale[c + 1], shift[c + 1]);
    float a2 = fmaf(v.z, scale[c + 2], shift[c + 2]);
    float a3 = fmaf(v.w, scale[c + 3], shift[c + 3]);
    v.x = a0 > 0.f ? a0 : 0.f;
    v.y = a1 > 0.f ? a1 : 0.f;
    v.z = a2 > 0.f ? a2 : 0.f;
    v.w = a3 > 0.f ? a3 : 0.f;
    out[i] = v;
}

extern "C" void kernel_launch(void* const* d_in, const int* in_sizes, int n_in,
                              void* d_out, int out_size, void* d_ws, size_t ws_size,
                              hipStream_t stream) {
    const float* x     = (const float*)d_in[0];          // [N, 64]
    const int*   eidx  = (const int*)d_in[1];            // [2, E]
    const float* W     = (const float*)d_in[2];          // [64, 64]
    // d_in[3] = b : cancels in BatchNorm (uniform per-column shift)
    const float* gamma = (const float*)d_in[4];          // [64]
    const float* beta  = (const float*)d_in[5];          // [64]
    float* out = (float*)d_out;                          // [N, 64]

    const int N = N_NODES;
    const int E = N_EDGES;
    const int total = N * DIM;

    const int* src = eidx;
    const int* dst = eidx + E;

    // workspace layout (~28.5 MB)
    unsigned short* hb = (unsigned short*)d_ws;            // (N+1)*DIM bf16; row N = zeros
    float* dinv      = (float*)(hb + (size_t)(N + 1) * DIM); // N
    int*   rowbeg    = (int*)(dinv + N);                   // N
    int*   rowend    = rowbeg + N;                         // N
    int*   cur       = rowend + N;                         // NBUCK } one
    float* gsum      = (float*)(cur + NBUCK);              // 64    } memset
    float* gsumsq    = gsum + 64;                          // 64    } region
    float* scale     = gsumsq + 64;                        // 64
    float* shift     = scale + 64;                         // 64
    unsigned int* entries = (unsigned int*)(shift + 64);   // NBUCK*CAP_OUT (11.2 MB)
    float* partial   = (float*)(entries + (size_t)NBUCK * CAP_OUT);  // GBLK*128 (3.2 MB)

    // zero cur + gsum + gsumsq, and the dummy hb row N
    hipMemsetAsync(cur, 0, (size_t)(NBUCK + 128) * sizeof(int), stream);
    hipMemsetAsync(hb + (size_t)N * DIM, 0, DIM * sizeof(unsigned short), stream);

    passA_kernel<<<ABLK, 1024, 0, stream>>>(src, dst, cur, entries, E);

    passB1_kernel<<<NBUCK, 256, 0, stream>>>(entries, cur, rowbeg, rowend, dinv, N);

    gemm_kernel<<<512, 256, 0, stream>>>(x, W, dinv, hb, N);

    gather_kernel<<<GBLK, 256, 0, stream>>>(rowbeg, rowend, entries, hb, dinv, out, partial, N);

    reduce2_kernel<<<50, 256, 0, stream>>>(partial, gsum);

    bn_finalize_kernel<<<1, 64, 0, stream>>>(gsum, gsumsq, gamma, beta, scale, shift, N);
    bn_apply_kernel<<<(total / 4 + 255) / 256, 256, 0, stream>>>((float4*)out, scale, shift, total / 4);
}